// Round 17
// baseline (6686.496 us; speedup 1.0000x reference)
//
#include <hip/hip_runtime.h>
#include <cmath>

#define LEAK 0.95f
#define ILEAK 0.05f

typedef float f4 __attribute__((ext_vector_type(4)));
typedef short s8 __attribute__((ext_vector_type(8)));   // 8 bf16 = 4 VGPRs
typedef unsigned long long ull;

// ---------------- Phase 1: u = x @ W_in^T (fp32 tiled GEMM) ----------------
__global__ __launch_bounds__(256) void resv_gemm_uin(
    const float* __restrict__ A, const float* __restrict__ Bm,
    float* __restrict__ C, int M, int N, int K)
{
    __shared__ float As[16][68];
    __shared__ float Bs[16][68];
    const int tid = threadIdx.x;
    const int m0 = blockIdx.y * 64;
    const int n0 = blockIdx.x * 64;
    const int lm = tid >> 2;
    const int lk = (tid & 3) * 4;
    const int ty = tid >> 4;
    const int tx = tid & 15;

    float acc[4][4];
#pragma unroll
    for (int i = 0; i < 4; ++i)
#pragma unroll
        for (int j = 0; j < 4; ++j) acc[i][j] = 0.f;

    const float* Aptr = A + (size_t)(m0 + lm) * K + lk;
    const float* Bptr = Bm + (size_t)(n0 + lm) * K + lk;

    for (int k0 = 0; k0 < K; k0 += 16) {
        float4 av = *(const float4*)(Aptr + k0);
        float4 bv = *(const float4*)(Bptr + k0);
        __syncthreads();
        As[lk + 0][lm] = av.x; As[lk + 1][lm] = av.y;
        As[lk + 2][lm] = av.z; As[lk + 3][lm] = av.w;
        Bs[lk + 0][lm] = bv.x; Bs[lk + 1][lm] = bv.y;
        Bs[lk + 2][lm] = bv.z; Bs[lk + 3][lm] = bv.w;
        __syncthreads();
#pragma unroll
        for (int kk = 0; kk < 16; ++kk) {
            float4 a = *(const float4*)(&As[kk][ty * 4]);
            float4 b = *(const float4*)(&Bs[kk][tx * 4]);
            acc[0][0] += a.x * b.x; acc[0][1] += a.x * b.y; acc[0][2] += a.x * b.z; acc[0][3] += a.x * b.w;
            acc[1][0] += a.y * b.x; acc[1][1] += a.y * b.y; acc[1][2] += a.y * b.z; acc[1][3] += a.y * b.w;
            acc[2][0] += a.z * b.x; acc[2][1] += a.z * b.y; acc[2][2] += a.z * b.z; acc[2][3] += a.z * b.w;
            acc[3][0] += a.w * b.x; acc[3][1] += a.w * b.y; acc[3][2] += a.w * b.z; acc[3][3] += a.w * b.w;
        }
    }
    float* Cp = C + (size_t)(m0 + ty * 4) * N + n0 + tx * 4;
#pragma unroll
    for (int i = 0; i < 4; ++i) {
        float4 v = make_float4(acc[i][0], acc[i][1], acc[i][2], acc[i][3]);
        *(float4*)(Cp + (size_t)i * N) = v;
    }
}

__device__ __forceinline__ unsigned f32_to_bf16_rne(float x) {
    unsigned u = __float_as_uint(x);
    return (u + 0x7FFFu + ((u >> 16) & 1u)) >> 16;
}

// ---------------- Phase 2: reservoir recurrence, MFMA + bf16 exchange -----
// r16 structure with the exchange payload shrunk to what consumers need:
// states cross wgs as PACKED BF16 pairs (tag16|bf16|tag16|bf16 per 8B ull;
// tag = step, 8B atomic -> no tearing; memset-0 = tag0 + bf16 0 = step-0
// init). Producer converts once (same RNE bits as r16 -> numerics
// identical); consumers poll HALF the loads (8/lane) in a SINGLE phase
// (r12's sentinel+bulk 2-RTT serialization collapsed), unpack straight to
// Bb via 8 ds_write_b32. Bb and red double-buffered on t&1 -> 2 barriers.
// MFMA: 16x16x32 bf16, W as 16 A-frags (64 VGPR); A/B share the slot->k
// map so any HW-map mismatch is a common k-permutation that cancels.
__global__ __launch_bounds__(256, 1) void resv_recur(
    const float* __restrict__ Wres,   // [1024][1024]
    float* __restrict__ out,          // [32][2048][1024] (pre-filled with u)
    ull* __restrict__ pairs)          // ws: [2 slots][8 g][4 b][512 hp] ulls
{
    constexpr int H = 1024, S = 2048;
    extern __shared__ char smraw[];
    ushort* Bb  = (ushort*)smraw;                 // [2][4 b][1040] bf16 (16640 B)
    float*  uL  = (float*)(smraw + 16640);        // [2][2048] u dbuf (16 KB)
    float*  red = (float*)(smraw + 16640 + 16384);// [2][4 q][32 row][4 b] (4 KB)

    const int tid = threadIdx.x;
    const int g  = blockIdx.x & 7;
    const int r  = blockIdx.x >> 3;
    const int h0 = r * 32;
    const int b0 = g * 4;

    const int w  = tid >> 6;           // wave = k-quarter (k in [w*256, +256))
    const int l  = tid & 63;
    const int lg = l >> 4;             // lane-group 0..3
    const int lc = l & 15;             // A-row / B-col / C-col index

    // ---- one-time: W A-fragments, 2 M-tiles x 8 K-tiles, slot k-map
    //      k = w*256 + kt*32 + lg*8 + j (contiguous 8) ----
    s8 Afrag[16];
#pragma unroll
    for (int m = 0; m < 2; ++m)
#pragma unroll
        for (int kt = 0; kt < 8; ++kt) {
            const float* wp = Wres + (size_t)(h0 + m * 16 + lc) * H
                            + (w * 256 + kt * 32 + lg * 8);
            s8 a;
#pragma unroll
            for (int j = 0; j < 8; ++j) a[j] = (short)f32_to_bf16_rne(wp[j]);
            Afrag[m * 8 + kt] = a;
        }

    const int fb  = tid & 3;           // finish: batch
    const int frw = tid >> 2;          // finish: row (tid<128 -> frw<32)
    float pv = 0.f;                    // finish thread's own previous value

    for (int t = 0; t < S; ++t) {
        const int p = t & 1;
        // ---- stage u[t..t+15] into double buffer (own region, plain) ----
        if ((t & 15) == 0) {
            float* uB = uL + ((t >> 4) & 1) * 2048;
            for (int c = tid; c < 512; c += 256) {
                int rw4 = c & 7, b = (c >> 3) & 3, tt = c >> 5;
                const float4* src =
                    (const float4*)(out + ((size_t)(b0 + b) * S + (t + tt)) * H + h0);
                ((float4*)uB)[(tt * 4 + b) * 8 + rw4] = src[rw4];
            }
        }
        // ---- single-phase poll: 8 packed ulls/lane, retry until fresh ----
        {
            const ull* src = pairs + ((size_t)(p * 8 + g)) * 2048;
            const ull tg = (ull)(unsigned short)t;
            const ull tpat = (tg << 48) | (tg << 16);
            ull v[8];
            for (;;) {
#pragma unroll
                for (int c = 0; c < 8; ++c)
                    v[c] = __hip_atomic_load(src + c * 256 + tid, __ATOMIC_RELAXED,
                                             __HIP_MEMORY_SCOPE_AGENT);
                int ok = 1;
#pragma unroll
                for (int c = 0; c < 8; ++c)
                    ok &= ((v[c] & 0xFFFF0000FFFF0000ull) == tpat);
                if (__all(ok)) break;
            }
            // unpack straight to Bb[p]: one b32 write = 2 bf16 (h even, h+1)
            uint* bw = (uint*)(Bb + (size_t)p * 4160);
#pragma unroll
            for (int c = 0; c < 8; ++c) {
                int idx = c * 256 + tid;              // = b*512 + hpair
                uint word = (uint)(v[c] & 0xFFFFu)
                          | ((uint)((v[c] >> 32) & 0xFFFFu) << 16);
                bw[(idx >> 9) * 520 + (idx & 511)] = word;
            }
        }
        __syncthreads();   // barrier 1: Bb[p] complete

        // ---- compute: 16 MFMA per wave (2 M-tiles x 8 K-tiles) ----
        {
            const ushort* bbase = Bb + (size_t)p * 4160 + (lc & 3) * 1040
                                + w * 256 + lg * 8;
            f4 c0 = (f4)(0.f), c1 = (f4)(0.f);
#pragma unroll
            for (int kt = 0; kt < 8; ++kt) {
                s8 bf = *(const s8*)(bbase + kt * 32);
                c0 = __builtin_amdgcn_mfma_f32_16x16x32_bf16(Afrag[kt],     bf, c0, 0, 0, 0);
                c1 = __builtin_amdgcn_mfma_f32_16x16x32_bf16(Afrag[8 + kt], bf, c1, 0, 0, 0);
            }
            // C/D: col=l&15, row=4*(l>>4)+j (m89). Only cols 0..3 are real.
            float* redB = red + p * 512;
            if (lc < 4) {
#pragma unroll
                for (int j = 0; j < 4; ++j) {
                    redB[(w * 32 + lg * 4 + j) * 4 + lc]      = c0[j];
                    redB[(w * 32 + 16 + lg * 4 + j) * 4 + lc] = c1[j];
                }
            }
        }
        __syncthreads();   // barrier 2: red[p] complete

        // ---- finish (tid<128): publish packed bf16 pair, then out ----
        if (tid < 128) {
            const float* redB = red + p * 512;
            float sum = redB[(0 * 32 + frw) * 4 + fb] + redB[(1 * 32 + frw) * 4 + fb]
                      + redB[(2 * 32 + frw) * 4 + fb] + redB[(3 * 32 + frw) * 4 + fb];
            float uv = uL[((t >> 4) & 1) * 2048 + (((t & 15) * 4 + fb) << 5) + frw];
            float ns = LEAK * tanhf(uv + sum) + ILEAK * pv;
            pv = ns;
            unsigned nb = f32_to_bf16_rne(ns);
            unsigned hb = (unsigned)__shfl_xor((int)nb, 4, 64);  // partner h^1
            if ((tid & 4) == 0) {      // frw even: pack (h, h+1), full lines
                ull T = (ull)(unsigned short)(t + 1);
                ull pk = (T << 48) | ((ull)hb << 32) | (T << 16) | (ull)nb;
                __hip_atomic_store(
                    pairs + ((size_t)(((t + 1) & 1) * 8 + g)) * 2048
                          + fb * 512 + (h0 >> 1) + (frw >> 1),
                    pk, __ATOMIC_RELAXED, __HIP_MEMORY_SCOPE_AGENT);
            }
            out[((size_t)(b0 + fb) * S + t) * H + h0 + frw] = ns;
        }
        // no barrier 3: Bb/red double-buffered; next-step writes hit buffer
        // p^1, and buffer p is not rewritten until after two more barriers.
    }
}

extern "C" void kernel_launch(void* const* d_in, const int* in_sizes, int n_in,
                              void* d_out, int out_size, void* d_ws, size_t ws_size,
                              hipStream_t stream)
{
    const float* x    = (const float*)d_in[0];   // [32][2048][512]
    const float* Win  = (const float*)d_in[1];   // [1024][512]
    const float* Wres = (const float*)d_in[2];   // [1024][1024]
    float* out = (float*)d_out;                  // [32][2048][1024]

    ull* pairs = (ull*)d_ws;                     // 2*8*2048*8 = 262144 B

    // zero pairs every launch: (tag 0, bf16 0) == step-0 initial state
    hipMemsetAsync(d_ws, 0, 262144, stream);

    // phase 1: u = x @ W_in^T into d_out
    dim3 gemm_grid(1024 / 64, 65536 / 64);
    resv_gemm_uin<<<gemm_grid, 256, 0, stream>>>(x, Win, out, 65536, 1024, 512);

    // phase 2: recurrence. 96KB dynamic LDS pins exactly 1 wg/CU
    // (co-residency of all 256 wgs proven rounds 1-16).
    constexpr int kLds = 96 * 1024;
    hipFuncSetAttribute((const void*)resv_recur,
                        hipFuncAttributeMaxDynamicSharedMemorySize, kLds);
    resv_recur<<<dim3(256), dim3(256), kLds, stream>>>(Wres, out, pairs);
}

// Round 18
// 6213.817 us; speedup vs baseline: 1.0761x; 1.0761x over previous
//
#include <hip/hip_runtime.h>
#include <cmath>

#define LEAK 0.95f
#define ILEAK 0.05f

typedef float f4 __attribute__((ext_vector_type(4)));
typedef short s8 __attribute__((ext_vector_type(8)));   // 8 bf16 = 4 VGPRs
typedef unsigned long long ull;

// ---------------- Phase 1: u = x @ W_in^T (fp32 tiled GEMM) ----------------
__global__ __launch_bounds__(256) void resv_gemm_uin(
    const float* __restrict__ A, const float* __restrict__ Bm,
    float* __restrict__ C, int M, int N, int K)
{
    __shared__ float As[16][68];
    __shared__ float Bs[16][68];
    const int tid = threadIdx.x;
    const int m0 = blockIdx.y * 64;
    const int n0 = blockIdx.x * 64;
    const int lm = tid >> 2;
    const int lk = (tid & 3) * 4;
    const int ty = tid >> 4;
    const int tx = tid & 15;

    float acc[4][4];
#pragma unroll
    for (int i = 0; i < 4; ++i)
#pragma unroll
        for (int j = 0; j < 4; ++j) acc[i][j] = 0.f;

    const float* Aptr = A + (size_t)(m0 + lm) * K + lk;
    const float* Bptr = Bm + (size_t)(n0 + lm) * K + lk;

    for (int k0 = 0; k0 < K; k0 += 16) {
        float4 av = *(const float4*)(Aptr + k0);
        float4 bv = *(const float4*)(Bptr + k0);
        __syncthreads();
        As[lk + 0][lm] = av.x; As[lk + 1][lm] = av.y;
        As[lk + 2][lm] = av.z; As[lk + 3][lm] = av.w;
        Bs[lk + 0][lm] = bv.x; Bs[lk + 1][lm] = bv.y;
        Bs[lk + 2][lm] = bv.z; Bs[lk + 3][lm] = bv.w;
        __syncthreads();
#pragma unroll
        for (int kk = 0; kk < 16; ++kk) {
            float4 a = *(const float4*)(&As[kk][ty * 4]);
            float4 b = *(const float4*)(&Bs[kk][tx * 4]);
            acc[0][0] += a.x * b.x; acc[0][1] += a.x * b.y; acc[0][2] += a.x * b.z; acc[0][3] += a.x * b.w;
            acc[1][0] += a.y * b.x; acc[1][1] += a.y * b.y; acc[1][2] += a.y * b.z; acc[1][3] += a.y * b.w;
            acc[2][0] += a.z * b.x; acc[2][1] += a.z * b.y; acc[2][2] += a.z * b.z; acc[2][3] += a.z * b.w;
            acc[3][0] += a.w * b.x; acc[3][1] += a.w * b.y; acc[3][2] += a.w * b.z; acc[3][3] += a.w * b.w;
        }
    }
    float* Cp = C + (size_t)(m0 + ty * 4) * N + n0 + tx * 4;
#pragma unroll
    for (int i = 0; i < 4; ++i) {
        float4 v = make_float4(acc[i][0], acc[i][1], acc[i][2], acc[i][3]);
        *(float4*)(Cp + (size_t)i * N) = v;
    }
}

__device__ __forceinline__ unsigned f32_to_bf16_rne(float x) {
    unsigned u = __float_as_uint(x);
    return (u + 0x7FFFu + ((u >> 16) & 1u)) >> 16;
}

// ---------------- Phase 2: reservoir recurrence, MFMA + bf16 exchange -----
// r17 (packed bf16 tag-exchange, single-phase 8-load poll) with BARRIER 3
// RESTORED -- the one change vs r17. Without it, waves 2-3 (non-publishers)
// raced into the next step's poll BEFORE waves 0-1 issued their state
// stores; their tight spin competed with the publishes for the CU's VMEM
// path and L3, delaying the data everyone polls for (r17: 5.9ms vs r16
// 4.5ms). Barrier 3's implicit vmcnt(0) drain restores r16's proven
// publish-then-poll ordering while keeping r17's halved exchange payload.
__global__ __launch_bounds__(256, 1) void resv_recur(
    const float* __restrict__ Wres,   // [1024][1024]
    float* __restrict__ out,          // [32][2048][1024] (pre-filled with u)
    ull* __restrict__ pairs)          // ws: [2 slots][8 g][4 b][512 hp] ulls
{
    constexpr int H = 1024, S = 2048;
    extern __shared__ char smraw[];
    ushort* Bb  = (ushort*)smraw;                 // [2][4 b][1040] bf16 (16640 B)
    float*  uL  = (float*)(smraw + 16640);        // [2][2048] u dbuf (16 KB)
    float*  red = (float*)(smraw + 16640 + 16384);// [2][4 q][32 row][4 b] (4 KB)

    const int tid = threadIdx.x;
    const int g  = blockIdx.x & 7;
    const int r  = blockIdx.x >> 3;
    const int h0 = r * 32;
    const int b0 = g * 4;

    const int w  = tid >> 6;           // wave = k-quarter (k in [w*256, +256))
    const int l  = tid & 63;
    const int lg = l >> 4;             // lane-group 0..3
    const int lc = l & 15;             // A-row / B-col / C-col index

    // ---- one-time: W A-fragments, 2 M-tiles x 8 K-tiles, slot k-map
    //      k = w*256 + kt*32 + lg*8 + j (contiguous 8) ----
    s8 Afrag[16];
#pragma unroll
    for (int m = 0; m < 2; ++m)
#pragma unroll
        for (int kt = 0; kt < 8; ++kt) {
            const float* wp = Wres + (size_t)(h0 + m * 16 + lc) * H
                            + (w * 256 + kt * 32 + lg * 8);
            s8 a;
#pragma unroll
            for (int j = 0; j < 8; ++j) a[j] = (short)f32_to_bf16_rne(wp[j]);
            Afrag[m * 8 + kt] = a;
        }

    const int fb  = tid & 3;           // finish: batch
    const int frw = tid >> 2;          // finish: row (tid<128 -> frw<32)
    float pv = 0.f;                    // finish thread's own previous value

    for (int t = 0; t < S; ++t) {
        const int p = t & 1;
        // ---- stage u[t..t+15] into double buffer (own region, plain) ----
        if ((t & 15) == 0) {
            float* uB = uL + ((t >> 4) & 1) * 2048;
            for (int c = tid; c < 512; c += 256) {
                int rw4 = c & 7, b = (c >> 3) & 3, tt = c >> 5;
                const float4* src =
                    (const float4*)(out + ((size_t)(b0 + b) * S + (t + tt)) * H + h0);
                ((float4*)uB)[(tt * 4 + b) * 8 + rw4] = src[rw4];
            }
        }
        // ---- single-phase poll: 8 packed ulls/lane, retry until fresh ----
        {
            const ull* src = pairs + ((size_t)(p * 8 + g)) * 2048;
            const ull tg = (ull)(unsigned short)t;
            const ull tpat = (tg << 48) | (tg << 16);
            ull v[8];
            for (;;) {
#pragma unroll
                for (int c = 0; c < 8; ++c)
                    v[c] = __hip_atomic_load(src + c * 256 + tid, __ATOMIC_RELAXED,
                                             __HIP_MEMORY_SCOPE_AGENT);
                int ok = 1;
#pragma unroll
                for (int c = 0; c < 8; ++c)
                    ok &= ((v[c] & 0xFFFF0000FFFF0000ull) == tpat);
                if (__all(ok)) break;
            }
            // unpack straight to Bb[p]: one b32 write = 2 bf16 (h even, h+1)
            uint* bw = (uint*)(Bb + (size_t)p * 4160);
#pragma unroll
            for (int c = 0; c < 8; ++c) {
                int idx = c * 256 + tid;              // = b*512 + hpair
                uint word = (uint)(v[c] & 0xFFFFu)
                          | ((uint)((v[c] >> 32) & 0xFFFFu) << 16);
                bw[(idx >> 9) * 520 + (idx & 511)] = word;
            }
        }
        __syncthreads();   // barrier 1: Bb[p] complete

        // ---- compute: 16 MFMA per wave (2 M-tiles x 8 K-tiles) ----
        {
            const ushort* bbase = Bb + (size_t)p * 4160 + (lc & 3) * 1040
                                + w * 256 + lg * 8;
            f4 c0 = (f4)(0.f), c1 = (f4)(0.f);
#pragma unroll
            for (int kt = 0; kt < 8; ++kt) {
                s8 bf = *(const s8*)(bbase + kt * 32);
                c0 = __builtin_amdgcn_mfma_f32_16x16x32_bf16(Afrag[kt],     bf, c0, 0, 0, 0);
                c1 = __builtin_amdgcn_mfma_f32_16x16x32_bf16(Afrag[8 + kt], bf, c1, 0, 0, 0);
            }
            // C/D: col=l&15, row=4*(l>>4)+j (m89). Only cols 0..3 are real.
            float* redB = red + p * 512;
            if (lc < 4) {
#pragma unroll
                for (int j = 0; j < 4; ++j) {
                    redB[(w * 32 + lg * 4 + j) * 4 + lc]      = c0[j];
                    redB[(w * 32 + 16 + lg * 4 + j) * 4 + lc] = c1[j];
                }
            }
        }
        __syncthreads();   // barrier 2: red[p] complete

        // ---- finish (tid<128): publish packed bf16 pair, then out ----
        if (tid < 128) {
            const float* redB = red + p * 512;
            float sum = redB[(0 * 32 + frw) * 4 + fb] + redB[(1 * 32 + frw) * 4 + fb]
                      + redB[(2 * 32 + frw) * 4 + fb] + redB[(3 * 32 + frw) * 4 + fb];
            float uv = uL[((t >> 4) & 1) * 2048 + (((t & 15) * 4 + fb) << 5) + frw];
            float ns = LEAK * tanhf(uv + sum) + ILEAK * pv;
            pv = ns;
            unsigned nb = f32_to_bf16_rne(ns);
            unsigned hb = (unsigned)__shfl_xor((int)nb, 4, 64);  // partner h^1
            if ((tid & 4) == 0) {      // frw even: pack (h, h+1), full lines
                ull T = (ull)(unsigned short)(t + 1);
                ull pk = (T << 48) | ((ull)hb << 32) | (T << 16) | (ull)nb;
                __hip_atomic_store(
                    pairs + ((size_t)(((t + 1) & 1) * 8 + g)) * 2048
                          + fb * 512 + (h0 >> 1) + (frw >> 1),
                    pk, __ATOMIC_RELAXED, __HIP_MEMORY_SCOPE_AGENT);
            }
            out[((size_t)(b0 + fb) * S + t) * H + h0 + frw] = ns;
        }
        // barrier 3 (restored): drain publishes to the coherence point
        // BEFORE any wave of this wg starts polling for t+1 -- keeps the
        // spin loops from queueing ahead of the publishes they wait on.
        __syncthreads();
    }
}

extern "C" void kernel_launch(void* const* d_in, const int* in_sizes, int n_in,
                              void* d_out, int out_size, void* d_ws, size_t ws_size,
                              hipStream_t stream)
{
    const float* x    = (const float*)d_in[0];   // [32][2048][512]
    const float* Win  = (const float*)d_in[1];   // [1024][512]
    const float* Wres = (const float*)d_in[2];   // [1024][1024]
    float* out = (float*)d_out;                  // [32][2048][1024]

    ull* pairs = (ull*)d_ws;                     // 2*8*2048*8 = 262144 B

    // zero pairs every launch: (tag 0, bf16 0) == step-0 initial state
    hipMemsetAsync(d_ws, 0, 262144, stream);

    // phase 1: u = x @ W_in^T into d_out
    dim3 gemm_grid(1024 / 64, 65536 / 64);
    resv_gemm_uin<<<gemm_grid, 256, 0, stream>>>(x, Win, out, 65536, 1024, 512);

    // phase 2: recurrence. 96KB dynamic LDS pins exactly 1 wg/CU
    // (co-residency of all 256 wgs proven rounds 1-17).
    constexpr int kLds = 96 * 1024;
    hipFuncSetAttribute((const void*)resv_recur,
                        hipFuncAttributeMaxDynamicSharedMemorySize, kLds);
    resv_recur<<<dim3(256), dim3(256), kLds, stream>>>(Wres, out, pairs);
}

// Round 19
// 5261.585 us; speedup vs baseline: 1.2708x; 1.1810x over previous
//
#include <hip/hip_runtime.h>
#include <cmath>

#define LEAK 0.95f
#define ILEAK 0.05f

typedef float f4 __attribute__((ext_vector_type(4)));
typedef short s8 __attribute__((ext_vector_type(8)));   // 8 bf16 = 4 VGPRs
typedef unsigned long long ull;

// ---------------- Phase 1: u = x @ W_in^T (fp32 tiled GEMM) ----------------
__global__ __launch_bounds__(256) void resv_gemm_uin(
    const float* __restrict__ A, const float* __restrict__ Bm,
    float* __restrict__ C, int M, int N, int K)
{
    __shared__ float As[16][68];
    __shared__ float Bs[16][68];
    const int tid = threadIdx.x;
    const int m0 = blockIdx.y * 64;
    const int n0 = blockIdx.x * 64;
    const int lm = tid >> 2;
    const int lk = (tid & 3) * 4;
    const int ty = tid >> 4;
    const int tx = tid & 15;

    float acc[4][4];
#pragma unroll
    for (int i = 0; i < 4; ++i)
#pragma unroll
        for (int j = 0; j < 4; ++j) acc[i][j] = 0.f;

    const float* Aptr = A + (size_t)(m0 + lm) * K + lk;
    const float* Bptr = Bm + (size_t)(n0 + lm) * K + lk;

    for (int k0 = 0; k0 < K; k0 += 16) {
        float4 av = *(const float4*)(Aptr + k0);
        float4 bv = *(const float4*)(Bptr + k0);
        __syncthreads();
        As[lk + 0][lm] = av.x; As[lk + 1][lm] = av.y;
        As[lk + 2][lm] = av.z; As[lk + 3][lm] = av.w;
        Bs[lk + 0][lm] = bv.x; Bs[lk + 1][lm] = bv.y;
        Bs[lk + 2][lm] = bv.z; Bs[lk + 3][lm] = bv.w;
        __syncthreads();
#pragma unroll
        for (int kk = 0; kk < 16; ++kk) {
            float4 a = *(const float4*)(&As[kk][ty * 4]);
            float4 b = *(const float4*)(&Bs[kk][tx * 4]);
            acc[0][0] += a.x * b.x; acc[0][1] += a.x * b.y; acc[0][2] += a.x * b.z; acc[0][3] += a.x * b.w;
            acc[1][0] += a.y * b.x; acc[1][1] += a.y * b.y; acc[1][2] += a.y * b.z; acc[1][3] += a.y * b.w;
            acc[2][0] += a.z * b.x; acc[2][1] += a.z * b.y; acc[2][2] += a.z * b.z; acc[2][3] += a.z * b.w;
            acc[3][0] += a.w * b.x; acc[3][1] += a.w * b.y; acc[3][2] += a.w * b.z; acc[3][3] += a.w * b.w;
        }
    }
    float* Cp = C + (size_t)(m0 + ty * 4) * N + n0 + tx * 4;
#pragma unroll
    for (int i = 0; i < 4; ++i) {
        float4 v = make_float4(acc[i][0], acc[i][1], acc[i][2], acc[i][3]);
        *(float4*)(Cp + (size_t)i * N) = v;
    }
}

__device__ __forceinline__ ushort f32_to_bf16_rne(float x) {
    unsigned u = __float_as_uint(x);
    return (ushort)((u + 0x7FFFu + ((u >> 16) & 1u)) >> 16);
}

// ---------------- Phase 2: reservoir recurrence, MFMA compute -------------
// BYTE-EXACT round-16 structure (proven best: 4.5ms recur) with ONE change:
// barrier 3 is a RAW s_barrier (no vmcnt drain). r16's __syncthreads there
// made finish waves wait ~700cy for the L3 ack of their own agent-scope
// publish stores before anyone could start polling t+1. The tag protocol
// only needs the stores ISSUED (stale polls retry; tags monotone), so the
// raw barrier keeps r17's lesson (no polling before publish-issue) while
// deleting the ack-wait. Leftover acks drain at next step's barrier 1, by
// which time the poll already proved they landed. WAR chains: red is read
// before barrier 3 and rewritten only after next barrier 1; uL dbuf'd.
__global__ __launch_bounds__(256, 1) void resv_recur(
    const float* __restrict__ Wres,   // [1024][1024]
    float* __restrict__ out,          // [32][2048][1024] (pre-filled with u)
    ull* __restrict__ pairs)          // ws: [2 slots][8 g][1024 h][4 b] pairs
{
    constexpr int H = 1024, S = 2048;
    extern __shared__ char smraw[];
    ushort* Bb  = (ushort*)smraw;               // [4 b][1040] bf16 (8320 B)
    float*  uL  = (float*)(smraw + 8448);       // [2][2048] u dbuf (16 KB)
    float*  red = (float*)(smraw + 8448 + 16384); // [4 q][32 row][4 b] (2 KB)

    const int tid = threadIdx.x;
    const int g  = blockIdx.x & 7;
    const int r  = blockIdx.x >> 3;
    const int h0 = r * 32;
    const int b0 = g * 4;

    const int w  = tid >> 6;           // wave = k-quarter (k in [w*256, +256))
    const int l  = tid & 63;
    const int lg = l >> 4;             // lane-group 0..3
    const int lc = l & 15;             // A-row / B-col / C-col index

    // ---- one-time: W A-fragments, 2 M-tiles x 8 K-tiles, slot k-map
    //      k = w*256 + kt*32 + lg*8 + j (contiguous 8) ----
    s8 Afrag[16];
#pragma unroll
    for (int m = 0; m < 2; ++m)
#pragma unroll
        for (int kt = 0; kt < 8; ++kt) {
            const float* wp = Wres + (size_t)(h0 + m * 16 + lc) * H
                            + (w * 256 + kt * 32 + lg * 8);
            s8 a;
#pragma unroll
            for (int j = 0; j < 8; ++j) a[j] = (short)f32_to_bf16_rne(wp[j]);
            Afrag[m * 8 + kt] = a;
        }

    const int fb  = tid & 3;           // finish: batch
    const int frw = tid >> 2;          // finish: row (tid<128 -> frw<32)
    float pv = 0.f;                    // finish thread's own previous value

    const ushort* bbase = Bb + (size_t)(lc & 3) * 1040 + w * 256 + lg * 8;

    for (int t = 0; t < S; ++t) {
        // ---- stage u[t..t+15] into double buffer (own region, plain) ----
        if ((t & 15) == 0) {
            float* uB = uL + ((t >> 4) & 1) * 2048;
            for (int c = tid; c < 512; c += 256) {
                int rw4 = c & 7, b = (c >> 3) & 3, tt = c >> 5;
                const float4* src =
                    (const float4*)(out + ((size_t)(b0 + b) * S + (t + tt)) * H + h0);
                ((float4*)uB)[(tt * 4 + b) * 8 + rw4] = src[rw4];
            }
        }
        // ---- poll: sentinel wait (4/lane), then bulk + verify (r12) ----
        {
            const ull* src = pairs + ((size_t)((t & 1) * 8 + g)) * 4096;
            const unsigned tgt = (unsigned)t;
            ull v[16];
            for (;;) {
                ull s0 = __hip_atomic_load(src + 0 * 256 + tid, __ATOMIC_RELAXED,
                                           __HIP_MEMORY_SCOPE_AGENT);
                ull s1 = __hip_atomic_load(src + 5 * 256 + tid, __ATOMIC_RELAXED,
                                           __HIP_MEMORY_SCOPE_AGENT);
                ull s2 = __hip_atomic_load(src + 10 * 256 + tid, __ATOMIC_RELAXED,
                                           __HIP_MEMORY_SCOPE_AGENT);
                ull s3 = __hip_atomic_load(src + 15 * 256 + tid, __ATOMIC_RELAXED,
                                           __HIP_MEMORY_SCOPE_AGENT);
                int ok = ((unsigned)(s0 >> 32) == tgt) & ((unsigned)(s1 >> 32) == tgt)
                       & ((unsigned)(s2 >> 32) == tgt) & ((unsigned)(s3 >> 32) == tgt);
                if (__all(ok)) { v[0] = s0; v[5] = s1; v[10] = s2; v[15] = s3; break; }
            }
            for (;;) {
                int ok = 1;
#pragma unroll
                for (int c = 0; c < 16; ++c) {
                    if (c == 0 || c == 5 || c == 10 || c == 15) continue;
                    v[c] = __hip_atomic_load(src + c * 256 + tid, __ATOMIC_RELAXED,
                                             __HIP_MEMORY_SCOPE_AGENT);
                    ok &= ((unsigned)(v[c] >> 32) == tgt);
                }
                if (__all(ok)) break;
            }
            // convert to bf16 and store to Bb[b][h] (stride 1040: writes are
            // 2-lanes-per-dword pairs across all 32 banks = conflict-free)
#pragma unroll
            for (int c = 0; c < 16; ++c) {
                int n = c * 256 + tid;           // n = h*4 + b
                Bb[(n & 3) * 1040 + (n >> 2)] =
                    f32_to_bf16_rne(__uint_as_float((unsigned)v[c]));
            }
        }
        __syncthreads();   // barrier 1: Bb complete

        // ---- compute: 16 MFMA per wave (2 M-tiles x 8 K-tiles) ----
        f4 c0 = (f4)(0.f), c1 = (f4)(0.f);
#pragma unroll
        for (int kt = 0; kt < 8; ++kt) {
            s8 bf = *(const s8*)(bbase + kt * 32);
            c0 = __builtin_amdgcn_mfma_f32_16x16x32_bf16(Afrag[kt],     bf, c0, 0, 0, 0);
            c1 = __builtin_amdgcn_mfma_f32_16x16x32_bf16(Afrag[8 + kt], bf, c1, 0, 0, 0);
        }
        // C/D: col=l&15, row=4*(l>>4)+j (m89). Only cols 0..3 are real.
        if (lc < 4) {
#pragma unroll
            for (int j = 0; j < 4; ++j) {
                red[(w * 32 + lg * 4 + j) * 4 + lc]      = c0[j];
                red[(w * 32 + 16 + lg * 4 + j) * 4 + lc] = c1[j];
            }
        }
        __syncthreads();   // barrier 2: red complete

        // ---- finish (tid<128): publish tagged pair, FULL-LINE order ----
        if (tid < 128) {
            float sum = red[(0 * 32 + frw) * 4 + fb] + red[(1 * 32 + frw) * 4 + fb]
                      + red[(2 * 32 + frw) * 4 + fb] + red[(3 * 32 + frw) * 4 + fb];
            float uv = uL[((t >> 4) & 1) * 2048 + (((t & 15) * 4 + fb) << 5) + frw];
            float ns = LEAK * tanhf(uv + sum) + ILEAK * pv;
            pv = ns;
            ull pk = ((ull)(unsigned)(t + 1) << 32) |
                     (ull)__float_as_uint(ns);
            __hip_atomic_store(
                pairs + ((size_t)(((t + 1) & 1) * 8 + g)) * 4096 + h0 * 4 + tid,
                pk, __ATOMIC_RELAXED, __HIP_MEMORY_SCOPE_AGENT);
            out[((size_t)(b0 + fb) * S + t) * H + h0 + frw] = ns;
        }
        // barrier 3 (RAW): order publish-ISSUE before polling, but skip the
        // vmcnt(0) drain (the ~700cy L3 ack of our own publishes). Stale
        // polls of in-flight lines simply retry -- tags are monotone.
        asm volatile("" ::: "memory");
        __builtin_amdgcn_s_barrier();
        asm volatile("" ::: "memory");
    }
}

extern "C" void kernel_launch(void* const* d_in, const int* in_sizes, int n_in,
                              void* d_out, int out_size, void* d_ws, size_t ws_size,
                              hipStream_t stream)
{
    const float* x    = (const float*)d_in[0];   // [32][2048][512]
    const float* Win  = (const float*)d_in[1];   // [1024][512]
    const float* Wres = (const float*)d_in[2];   // [1024][1024]
    float* out = (float*)d_out;                  // [32][2048][1024]

    ull* pairs = (ull*)d_ws;                     // 2*8*4096*8 = 524288 B

    // zero pairs every launch: (tag 0, 0.0f) == step-0 initial state
    hipMemsetAsync(d_ws, 0, 524288, stream);

    // phase 1: u = x @ W_in^T into d_out
    dim3 gemm_grid(1024 / 64, 65536 / 64);
    resv_gemm_uin<<<gemm_grid, 256, 0, stream>>>(x, Win, out, 65536, 1024, 512);

    // phase 2: recurrence. 96KB dynamic LDS pins exactly 1 wg/CU
    // (co-residency of all 256 wgs proven rounds 1-18).
    constexpr int kLds = 96 * 1024;
    hipFuncSetAttribute((const void*)resv_recur,
                        hipFuncAttributeMaxDynamicSharedMemorySize, kLds);
    resv_recur<<<dim3(256), dim3(256), kLds, stream>>>(Wres, out, pairs);
}